// Round 1
// baseline (516.495 us; speedup 1.0000x reference)
//
#include <hip/hip_runtime.h>
#include <hip/hip_bf16.h>

#define D_IN  32
#define D_EF  16
#define D_H   64
#define D_MSG 32
#define D_UP  32

// NOTE: __builtin_amdgcn_cvt_pkrtz / fdot2 use the __fp16-based vector type;
// _Float16-based ext vectors are treated as incompatible by clang.
typedef __fp16 v2h __attribute__((ext_vector_type(2)));

// bf16 helpers: pack two fp32 -> uint32 (RNE), unpack low/high half
__device__ __forceinline__ unsigned bf16pair(float a, float b) {
    unsigned ua = __float_as_uint(a);
    ua = (ua + 0x7fffu + ((ua >> 16) & 1u)) >> 16;
    unsigned ub = __float_as_uint(b);
    ub = (ub + 0x7fffu + ((ub >> 16) & 1u)) >> 16;
    return ua | (ub << 16);
}
__device__ __forceinline__ float bf_lo(unsigned u) { return __uint_as_float(u << 16); }
__device__ __forceinline__ float bf_hi(unsigned u) { return __uint_as_float(u & 0xffff0000u); }

// ---------------------------------------------------------------------------
// Fused front-end (independent stages dispatched by block range):
//   blocks [0, NBn)            : node_pre  (P1 fp32, P2 bf16 precompute)
//   blocks [NBn, NBn+NBe)      : hist + rank capture:
//                                  rank[e] = atomicAdd(&deg[dst[e]], 1)
//   block  NBn+NBe             : W1E pair-packing for fdot2
//   (W2 packing removed: layer-2 is hoisted out of the edge loop entirely —
//    agg = (Σ relu(h)) @ W2 + deg*b2, applied per-node in node_upd.)
// ---------------------------------------------------------------------------
__global__ __launch_bounds__(256) void prep_kernel(
    const float* __restrict__ x,
    const float* __restrict__ W1m,
    const float* __restrict__ b1m,
    const int*   __restrict__ ei,
    float* __restrict__ P1,
    unsigned short* __restrict__ P2b,
    int* __restrict__ deg,
    int* __restrict__ rank,
    v2h* __restrict__ W1Ep,
    int n_nodes, int n_edges, int NBn, int NBe)
{
    int b = blockIdx.x;

    if (b < NBn) {
        // ---------------- node_pre ----------------
        int i = b * 256 + threadIdx.x;
        if (i >= n_nodes) return;

        float xi[D_IN];
        const float4* xp = (const float4*)(x + (size_t)i * D_IN);
#pragma unroll
        for (int k4 = 0; k4 < D_IN / 4; ++k4) {
            float4 v = xp[k4];
            xi[4 * k4 + 0] = v.x; xi[4 * k4 + 1] = v.y;
            xi[4 * k4 + 2] = v.z; xi[4 * k4 + 3] = v.w;
        }
        {
            float acc[D_H];
#pragma unroll
            for (int j = 0; j < D_H; ++j) acc[j] = b1m[j];
            for (int k = 0; k < D_IN; ++k) {
                float xv = xi[k];
                const float* wr = W1m + (size_t)k * D_H;
#pragma unroll
                for (int j = 0; j < D_H; ++j) acc[j] += xv * wr[j];
            }
            float4* o = (float4*)(P1 + (size_t)i * D_H);
#pragma unroll
            for (int j4 = 0; j4 < D_H / 4; ++j4)
                o[j4] = make_float4(acc[4 * j4], acc[4 * j4 + 1],
                                    acc[4 * j4 + 2], acc[4 * j4 + 3]);
        }
        {
            float acc[D_H];
#pragma unroll
            for (int j = 0; j < D_H; ++j) acc[j] = 0.0f;
            for (int k = 0; k < D_IN; ++k) {
                float xv = xi[k];
                const float* wr = W1m + (size_t)(k + D_IN) * D_H;
#pragma unroll
                for (int j = 0; j < D_H; ++j) acc[j] += xv * wr[j];
            }
            uint4* o = (uint4*)(P2b + (size_t)i * D_H);
#pragma unroll
            for (int j8 = 0; j8 < D_H / 8; ++j8) {
                uint4 q;
                q.x = bf16pair(acc[8 * j8 + 0], acc[8 * j8 + 1]);
                q.y = bf16pair(acc[8 * j8 + 2], acc[8 * j8 + 3]);
                q.z = bf16pair(acc[8 * j8 + 4], acc[8 * j8 + 5]);
                q.w = bf16pair(acc[8 * j8 + 6], acc[8 * j8 + 7]);
                o[j8] = q;
            }
        }
    } else if (b < NBn + NBe) {
        // ---------------- hist + rank ----------------
        int e = (b - NBn) * 256 + threadIdx.x;
        if (e < n_edges)
            rank[e] = atomicAdd(&deg[ei[n_edges + e]], 1);
    } else {
        // ---------------- pack W1E for fdot2 ----------------
        int t = threadIdx.x;
        const float* W1E = W1m + (size_t)(2 * D_IN) * D_H;
        for (int idx = t; idx < 8 * D_H; idx += 256) {
            int kp = idx >> 6, c = idx & 63;
            W1Ep[idx] = __builtin_amdgcn_cvt_pkrtz(W1E[(2 * kp) * D_H + c],
                                                   W1E[(2 * kp + 1) * D_H + c]);
        }
    }
}

// ---------------------------------------------------------------------------
// 3-phase multi-block exclusive scan of deg -> offs
// ---------------------------------------------------------------------------
__global__ __launch_bounds__(256) void scan_partials_kernel(
    const int* __restrict__ deg, int* __restrict__ bsum, int n_nodes)
{
    int idx = blockIdx.x * 256 + threadIdx.x;
    int v = (idx < n_nodes) ? deg[idx] : 0;
#pragma unroll
    for (int o = 1; o < 64; o <<= 1) v += __shfl_xor(v, o, 64);
    __shared__ int ws[4];
    int lane = threadIdx.x & 63, w = threadIdx.x >> 6;
    if (lane == 0) ws[w] = v;
    __syncthreads();
    if (threadIdx.x == 0) bsum[blockIdx.x] = ws[0] + ws[1] + ws[2] + ws[3];
}

__global__ __launch_bounds__(256) void scan_blockoffs_kernel(
    const int* __restrict__ bsum, int* __restrict__ boffs, int nb)
{
    __shared__ int sdata[256];
    int t = threadIdx.x;
    sdata[t] = (t < nb) ? bsum[t] : 0;
    __syncthreads();
    for (int off = 1; off < 256; off <<= 1) {
        int u = (t >= off) ? sdata[t - off] : 0;
        __syncthreads();
        sdata[t] += u;
        __syncthreads();
    }
    if (t < nb) boffs[t] = (t > 0) ? sdata[t - 1] : 0;
}

__global__ __launch_bounds__(256) void scan_final_kernel(
    const int* __restrict__ deg, const int* __restrict__ boffs,
    int* __restrict__ offs, int n_nodes)
{
    __shared__ int sdata[256];
    int t = threadIdx.x;
    int idx = blockIdx.x * 256 + t;
    sdata[t] = (idx < n_nodes) ? deg[idx] : 0;
    __syncthreads();
    for (int off = 1; off < 256; off <<= 1) {
        int u = (t >= off) ? sdata[t - off] : 0;
        __syncthreads();
        sdata[t] += u;
        __syncthreads();
    }
    int excl = boffs[blockIdx.x] + ((t > 0) ? sdata[t - 1] : 0);
    if (idx < n_nodes) offs[idx] = excl;
}

// ---------------------------------------------------------------------------
// Atomic-free scatter: pos = offs[dst] + rank[e]  (unique by construction).
// Writes packed (edge_id, src) so gather never touches ei.
// ---------------------------------------------------------------------------
__global__ __launch_bounds__(256) void scatter_kernel(
    const int* __restrict__ ei,
    const int* __restrict__ rank,
    const int* __restrict__ offs,
    int2* __restrict__ edges_sorted,
    int n_edges)
{
    int e = blockIdx.x * blockDim.x + threadIdx.x;
    if (e < n_edges) {
        int s = ei[e];
        int d = ei[n_edges + e];
        int pos = offs[d] + rank[e];
        edges_sorted[pos] = make_int2(e, s);
    }
}

// ---------------------------------------------------------------------------
// Gather-aggregate, 16 threads per node. LAYER-2 HOISTED:
//   hsum[n] = Σ_edges relu( P1[n] + bf16(P2[src]) + ef · W1E )   (64 fp32/node)
// Only layer-1 (512 fdot2/edge) remains per-edge — the 64x32 W2 matmul is
// applied once per node in node_upd (linearity of segment_sum over shared W2).
// hacc[64] must stay register-resident -> chunk loop FULLY unrolled
// (runtime-indexed register arrays go to scratch).
// ---------------------------------------------------------------------------
__global__ __launch_bounds__(256) void gather_kernel(
    const float* __restrict__ ef,
    const v2h*  __restrict__ W1Ep,
    const float* __restrict__ P1,
    const unsigned short* __restrict__ P2b,
    const int*  __restrict__ deg,
    const int*  __restrict__ offs,
    const int2* __restrict__ edges_sorted,
    float* __restrict__ hagg,
    int n_nodes)
{
    int tid = blockIdx.x * blockDim.x + threadIdx.x;
    int n = tid >> 4;
    int t = tid & 15;
    if (n >= n_nodes) return;

    int start = offs[n];
    int end   = start + deg[n];
    const float* P1n = P1 + (size_t)n * D_H;

    float hacc[D_H];
#pragma unroll
    for (int c = 0; c < D_H; ++c) hacc[c] = 0.0f;

    int i = start + t;
    int s = 0;
    float4 ef0, ef1, ef2, ef3;
    if (i < end) {
        int2 es = edges_sorted[i];
        s = es.y;
        const float4* efp = (const float4*)(ef + (size_t)es.x * D_EF);
        ef0 = efp[0]; ef1 = efp[1]; ef2 = efp[2]; ef3 = efp[3];
    }

    while (i < end) {
        // ---- prefetch next edge (clamped -> unconditional, always valid) ----
        int inext = i + 16;
        int ip = (inext < end) ? inext : i;
        int2 es2 = edges_sorted[ip];
        const float4* efp2 = (const float4*)(ef + (size_t)es2.x * D_EF);
        float4 nf0 = efp2[0], nf1 = efp2[1], nf2 = efp2[2], nf3 = efp2[3];

        // current edge's ef -> fp16 pairs (k-pairs for dot2)
        v2h efh[D_EF / 2];
        efh[0] = __builtin_amdgcn_cvt_pkrtz(ef0.x, ef0.y);
        efh[1] = __builtin_amdgcn_cvt_pkrtz(ef0.z, ef0.w);
        efh[2] = __builtin_amdgcn_cvt_pkrtz(ef1.x, ef1.y);
        efh[3] = __builtin_amdgcn_cvt_pkrtz(ef1.z, ef1.w);
        efh[4] = __builtin_amdgcn_cvt_pkrtz(ef2.x, ef2.y);
        efh[5] = __builtin_amdgcn_cvt_pkrtz(ef2.z, ef2.w);
        efh[6] = __builtin_amdgcn_cvt_pkrtz(ef3.x, ef3.y);
        efh[7] = __builtin_amdgcn_cvt_pkrtz(ef3.z, ef3.w);

        const float4* p1  = (const float4*)P1n;
        const uint4*  p2u = (const uint4*)(P2b + (size_t)s * D_H);

#pragma unroll
        for (int j = 0; j < D_H / 8; ++j) {
            uint4 b = p2u[j];
            float4 a0 = p1[2 * j], a1 = p1[2 * j + 1];
            float h[8];
            h[0] = a0.x + bf_lo(b.x); h[1] = a0.y + bf_hi(b.x);
            h[2] = a0.z + bf_lo(b.y); h[3] = a0.w + bf_hi(b.y);
            h[4] = a1.x + bf_lo(b.z); h[5] = a1.y + bf_hi(b.z);
            h[6] = a1.z + bf_lo(b.w); h[7] = a1.w + bf_hi(b.w);

            // layer-1: h[c] += ef · W1E[:, 8j+c]  (8 k-pairs per column;
            // weight addresses wave-uniform -> s_load, feeds fdot2 SGPR slot)
#pragma unroll
            for (int kp = 0; kp < D_EF / 2; ++kp) {
                const v2h* wr = W1Ep + kp * D_H + 8 * j;
#pragma unroll
                for (int c8 = 0; c8 < 8; ++c8)
                    h[c8] = __builtin_amdgcn_fdot2(efh[kp], wr[c8], h[c8], false);
            }

            // relu + accumulate into per-lane partial h-sum (static indices)
#pragma unroll
            for (int c8 = 0; c8 < 8; ++c8) {
                float r = h[c8] > 0.0f ? h[c8] : 0.0f;
                hacc[8 * j + c8] += r;
            }
        }

        i = inext; s = es2.y;
        ef0 = nf0; ef1 = nf1; ef2 = nf2; ef3 = nf3;
    }

    // ---- 4-stage butterfly compaction across the node's 16 lanes ----
    // Each stage halves the live component set (keep-half chosen by a lane
    // bit via cndmask). 120 shuffles vs 256 for the naive all-comp reduce.
    // Final: lane t owns comps [4t, 4t+4) -> one coalesced float4 store/lane.
    float r1[32];
    {
        const bool up = (t & 8) != 0;
#pragma unroll
        for (int c = 0; c < 32; ++c) {
            float lo = hacc[c]      + __shfl_xor(hacc[c],      8, 16);
            float hi = hacc[c + 32] + __shfl_xor(hacc[c + 32], 8, 16);
            r1[c] = up ? hi : lo;
        }
    }
    float r2[16];
    {
        const bool up = (t & 4) != 0;
#pragma unroll
        for (int c = 0; c < 16; ++c) {
            float lo = r1[c]      + __shfl_xor(r1[c],      4, 16);
            float hi = r1[c + 16] + __shfl_xor(r1[c + 16], 4, 16);
            r2[c] = up ? hi : lo;
        }
    }
    float r3[8];
    {
        const bool up = (t & 2) != 0;
#pragma unroll
        for (int c = 0; c < 8; ++c) {
            float lo = r2[c]     + __shfl_xor(r2[c],     2, 16);
            float hi = r2[c + 8] + __shfl_xor(r2[c + 8], 2, 16);
            r3[c] = up ? hi : lo;
        }
    }
    float r4[4];
    {
        const bool up = (t & 1) != 0;
#pragma unroll
        for (int c = 0; c < 4; ++c) {
            float lo = r3[c]     + __shfl_xor(r3[c],     1, 16);
            float hi = r3[c + 4] + __shfl_xor(r3[c + 4], 1, 16);
            r4[c] = up ? hi : lo;
        }
    }

    ((float4*)(hagg + (size_t)n * D_H))[t] =
        make_float4(r4[0], r4[1], r4[2], r4[3]);
}

// ---------------------------------------------------------------------------
// Per-node update MLP. Absorbs the hoisted layer-2:
//   aggm = hsum @ W2m + deg*b2m          (2048 MACs/node, once per NODE)
//   out  = relu([x, aggm] @ W1u + b1u) @ W2u + b2u
// ---------------------------------------------------------------------------
__global__ __launch_bounds__(256) void node_upd_kernel(
    const float* __restrict__ x,
    const float* __restrict__ hagg,
    const int*   __restrict__ deg,
    const float* __restrict__ b2m,
    const float* __restrict__ W2m,
    const float* __restrict__ W1u,
    const float* __restrict__ b1u,
    const float* __restrict__ W2u,
    const float* __restrict__ b2u,
    float* __restrict__ out,
    int n_nodes)
{
    int i = blockIdx.x * blockDim.x + threadIdx.x;
    if (i >= n_nodes) return;

    float in[D_IN + D_MSG];
    const float4* xp = (const float4*)(x + (size_t)i * D_IN);
#pragma unroll
    for (int k4 = 0; k4 < D_IN / 4; ++k4) {
        float4 v = xp[k4];
        in[4 * k4 + 0] = v.x; in[4 * k4 + 1] = v.y;
        in[4 * k4 + 2] = v.z; in[4 * k4 + 3] = v.w;
    }

    float dc = (float)deg[i];
#pragma unroll
    for (int m = 0; m < D_MSG; ++m) in[D_IN + m] = dc * b2m[m];

    const float4* hp = (const float4*)(hagg + (size_t)i * D_H);
    for (int j4 = 0; j4 < D_H / 4; ++j4) {
        float4 v = hp[j4];
        const float* w0 = W2m + (size_t)(4 * j4 + 0) * D_MSG;
        const float* w1 = W2m + (size_t)(4 * j4 + 1) * D_MSG;
        const float* w2 = W2m + (size_t)(4 * j4 + 2) * D_MSG;
        const float* w3 = W2m + (size_t)(4 * j4 + 3) * D_MSG;
#pragma unroll
        for (int m = 0; m < D_MSG; ++m)
            in[D_IN + m] += v.x * w0[m] + v.y * w1[m] + v.z * w2[m] + v.w * w3[m];
    }

    float h[D_H];
#pragma unroll
    for (int j = 0; j < D_H; ++j) h[j] = b1u[j];
    for (int k = 0; k < D_IN + D_MSG; ++k) {
        float v = in[k];
        const float* wr = W1u + (size_t)k * D_H;
#pragma unroll
        for (int j = 0; j < D_H; ++j) h[j] += v * wr[j];
    }

    float o[D_UP];
#pragma unroll
    for (int m = 0; m < D_UP; ++m) o[m] = b2u[m];
    for (int j = 0; j < D_H; ++j) {
        float r = h[j] > 0.0f ? h[j] : 0.0f;
        const float* wr = W2u + (size_t)j * D_UP;
#pragma unroll
        for (int m = 0; m < D_UP; ++m) o[m] += r * wr[m];
    }

    float4* op = (float4*)(out + (size_t)i * D_UP);
#pragma unroll
    for (int m4 = 0; m4 < D_UP / 4; ++m4)
        op[m4] = make_float4(o[4 * m4], o[4 * m4 + 1], o[4 * m4 + 2], o[4 * m4 + 3]);
}

extern "C" void kernel_launch(void* const* d_in, const int* in_sizes, int n_in,
                              void* d_out, int out_size, void* d_ws, size_t ws_size,
                              hipStream_t stream) {
    const float* x    = (const float*)d_in[0];
    // d_in[1] = degrees — unused by the reference computation
    const float* ef   = (const float*)d_in[2];
    const float* W1m  = (const float*)d_in[3];
    const float* b1m  = (const float*)d_in[4];
    const float* W2m  = (const float*)d_in[5];
    const float* b2m  = (const float*)d_in[6];
    const float* W1u  = (const float*)d_in[7];
    const float* b1u  = (const float*)d_in[8];
    const float* W2u  = (const float*)d_in[9];
    const float* b2u  = (const float*)d_in[10];
    const int*   ei   = (const int*)d_in[11];

    const int n_nodes = in_sizes[0] / D_IN;      // 50000
    const int n_edges = in_sizes[11] / 2;        // 1600000

    float* out = (float*)d_out;

    const int NBn = (n_nodes + 255) / 256;       // 196 node blocks (<=256 req'd for scan)
    const int NBe = (n_edges + 255) / 256;       // 6250 edge blocks

    // Workspace layout (~45.2 MB, same footprint as before):
    //   P1           : n_nodes * D_H    f    (12.8 MB)
    //   P2b          : n_nodes * D_H    u16  (6.4 MB)
    //   edges_sorted : n_edges          int2 (12.8 MB)
    //   deg/offs     : n_nodes          i
    //   bsum/boffs   : NBn              i
    //   W1Ep         : 8*64   v2h (2 KB)
    //   tail (ALIASED by lifetime):
    //     rank : n_edges i     (6.4 MB,  live prep -> scatter)
    //     hagg : n_nodes*D_H f (12.8 MB, live gather -> node_upd)
    float*          P1  = (float*)d_ws;
    unsigned short* P2b = (unsigned short*)(P1 + (size_t)n_nodes * D_H);
    int2* edges_sorted  = (int2*)(P2b + (size_t)n_nodes * D_H);
    int* deg    = (int*)(edges_sorted + n_edges);
    int* offs   = deg    + n_nodes;
    int* bsum   = offs   + n_nodes;
    int* boffs  = bsum   + NBn;
    v2h* W1Ep   = (v2h*)(boffs + NBn);
    int*   rank = (int*)(W1Ep + 8 * D_H);
    float* hagg = (float*)rank;                  // aliases rank (disjoint lifetime)

    hipMemsetAsync(deg, 0, (size_t)n_nodes * sizeof(int), stream);

    prep_kernel<<<NBn + NBe + 1, 256, 0, stream>>>(
        x, W1m, b1m, ei, P1, P2b, deg, rank, W1Ep,
        n_nodes, n_edges, NBn, NBe);

    scan_partials_kernel<<<NBn, 256, 0, stream>>>(deg, bsum, n_nodes);
    scan_blockoffs_kernel<<<1, 256, 0, stream>>>(bsum, boffs, NBn);
    scan_final_kernel<<<NBn, 256, 0, stream>>>(deg, boffs, offs, n_nodes);

    scatter_kernel<<<NBe, 256, 0, stream>>>(ei, rank, offs, edges_sorted, n_edges);

    {
        long total = (long)n_nodes * 16;
        int grid = (int)((total + 255) / 256);
        gather_kernel<<<grid, 256, 0, stream>>>(ef, W1Ep, P1, P2b,
                                                deg, offs, edges_sorted, hagg,
                                                n_nodes);
    }
    node_upd_kernel<<<NBn, 256, 0, stream>>>(x, hagg, deg, b2m, W2m,
                                             W1u, b1u, W2u, b2u, out, n_nodes);
}

// Round 2
// 450.026 us; speedup vs baseline: 1.1477x; 1.1477x over previous
//
#include <hip/hip_runtime.h>
#include <hip/hip_bf16.h>

#define D_IN  32
#define D_EF  16
#define D_H   64
#define D_MSG 32
#define D_UP  32

// NOTE: __builtin_amdgcn_cvt_pkrtz / fdot2 use the __fp16-based vector type;
// _Float16-based ext vectors are treated as incompatible by clang.
typedef __fp16 v2h __attribute__((ext_vector_type(2)));

// bf16 helpers: pack two fp32 -> uint32 (RNE), unpack low/high half
__device__ __forceinline__ unsigned bf16pair(float a, float b) {
    unsigned ua = __float_as_uint(a);
    ua = (ua + 0x7fffu + ((ua >> 16) & 1u)) >> 16;
    unsigned ub = __float_as_uint(b);
    ub = (ub + 0x7fffu + ((ub >> 16) & 1u)) >> 16;
    return ua | (ub << 16);
}
__device__ __forceinline__ float bf_lo(unsigned u) { return __uint_as_float(u << 16); }
__device__ __forceinline__ float bf_hi(unsigned u) { return __uint_as_float(u & 0xffff0000u); }

// ---------------------------------------------------------------------------
// Fused front-end (independent stages dispatched by block range):
//   blocks [0, NBn)            : node_pre  (P1 fp32, P2 bf16 precompute)
//   blocks [NBn, NBn+NBe)      : hist + rank capture:
//                                  rank[e] = atomicAdd(&deg[dst[e]], 1)
//   block  NBn+NBe             : W1E pair-packing for fdot2
// ---------------------------------------------------------------------------
__global__ __launch_bounds__(256) void prep_kernel(
    const float* __restrict__ x,
    const float* __restrict__ W1m,
    const float* __restrict__ b1m,
    const int*   __restrict__ ei,
    float* __restrict__ P1,
    unsigned short* __restrict__ P2b,
    int* __restrict__ deg,
    int* __restrict__ rank,
    v2h* __restrict__ W1Ep,
    int n_nodes, int n_edges, int NBn, int NBe)
{
    int b = blockIdx.x;

    if (b < NBn) {
        // ---------------- node_pre ----------------
        int i = b * 256 + threadIdx.x;
        if (i >= n_nodes) return;

        float xi[D_IN];
        const float4* xp = (const float4*)(x + (size_t)i * D_IN);
#pragma unroll
        for (int k4 = 0; k4 < D_IN / 4; ++k4) {
            float4 v = xp[k4];
            xi[4 * k4 + 0] = v.x; xi[4 * k4 + 1] = v.y;
            xi[4 * k4 + 2] = v.z; xi[4 * k4 + 3] = v.w;
        }
        {
            float acc[D_H];
#pragma unroll
            for (int j = 0; j < D_H; ++j) acc[j] = b1m[j];
            for (int k = 0; k < D_IN; ++k) {
                float xv = xi[k];
                const float* wr = W1m + (size_t)k * D_H;
#pragma unroll
                for (int j = 0; j < D_H; ++j) acc[j] += xv * wr[j];
            }
            float4* o = (float4*)(P1 + (size_t)i * D_H);
#pragma unroll
            for (int j4 = 0; j4 < D_H / 4; ++j4)
                o[j4] = make_float4(acc[4 * j4], acc[4 * j4 + 1],
                                    acc[4 * j4 + 2], acc[4 * j4 + 3]);
        }
        {
            float acc[D_H];
#pragma unroll
            for (int j = 0; j < D_H; ++j) acc[j] = 0.0f;
            for (int k = 0; k < D_IN; ++k) {
                float xv = xi[k];
                const float* wr = W1m + (size_t)(k + D_IN) * D_H;
#pragma unroll
                for (int j = 0; j < D_H; ++j) acc[j] += xv * wr[j];
            }
            uint4* o = (uint4*)(P2b + (size_t)i * D_H);
#pragma unroll
            for (int j8 = 0; j8 < D_H / 8; ++j8) {
                uint4 q;
                q.x = bf16pair(acc[8 * j8 + 0], acc[8 * j8 + 1]);
                q.y = bf16pair(acc[8 * j8 + 2], acc[8 * j8 + 3]);
                q.z = bf16pair(acc[8 * j8 + 4], acc[8 * j8 + 5]);
                q.w = bf16pair(acc[8 * j8 + 6], acc[8 * j8 + 7]);
                o[j8] = q;
            }
        }
    } else if (b < NBn + NBe) {
        // ---------------- hist + rank ----------------
        int e = (b - NBn) * 256 + threadIdx.x;
        if (e < n_edges)
            rank[e] = atomicAdd(&deg[ei[n_edges + e]], 1);
    } else {
        // ---------------- pack W1E for fdot2 ----------------
        int t = threadIdx.x;
        const float* W1E = W1m + (size_t)(2 * D_IN) * D_H;
        for (int idx = t; idx < 8 * D_H; idx += 256) {
            int kp = idx >> 6, c = idx & 63;
            W1Ep[idx] = __builtin_amdgcn_cvt_pkrtz(W1E[(2 * kp) * D_H + c],
                                                   W1E[(2 * kp + 1) * D_H + c]);
        }
    }
}

// ---------------------------------------------------------------------------
// 3-phase multi-block exclusive scan of deg -> offs
// ---------------------------------------------------------------------------
__global__ __launch_bounds__(256) void scan_partials_kernel(
    const int* __restrict__ deg, int* __restrict__ bsum, int n_nodes)
{
    int idx = blockIdx.x * 256 + threadIdx.x;
    int v = (idx < n_nodes) ? deg[idx] : 0;
#pragma unroll
    for (int o = 1; o < 64; o <<= 1) v += __shfl_xor(v, o, 64);
    __shared__ int ws[4];
    int lane = threadIdx.x & 63, w = threadIdx.x >> 6;
    if (lane == 0) ws[w] = v;
    __syncthreads();
    if (threadIdx.x == 0) bsum[blockIdx.x] = ws[0] + ws[1] + ws[2] + ws[3];
}

__global__ __launch_bounds__(256) void scan_blockoffs_kernel(
    const int* __restrict__ bsum, int* __restrict__ boffs, int nb)
{
    __shared__ int sdata[256];
    int t = threadIdx.x;
    sdata[t] = (t < nb) ? bsum[t] : 0;
    __syncthreads();
    for (int off = 1; off < 256; off <<= 1) {
        int u = (t >= off) ? sdata[t - off] : 0;
        __syncthreads();
        sdata[t] += u;
        __syncthreads();
    }
    if (t < nb) boffs[t] = (t > 0) ? sdata[t - 1] : 0;
}

__global__ __launch_bounds__(256) void scan_final_kernel(
    const int* __restrict__ deg, const int* __restrict__ boffs,
    int* __restrict__ offs, int n_nodes)
{
    __shared__ int sdata[256];
    int t = threadIdx.x;
    int idx = blockIdx.x * 256 + t;
    sdata[t] = (idx < n_nodes) ? deg[idx] : 0;
    __syncthreads();
    for (int off = 1; off < 256; off <<= 1) {
        int u = (t >= off) ? sdata[t - off] : 0;
        __syncthreads();
        sdata[t] += u;
        __syncthreads();
    }
    int excl = boffs[blockIdx.x] + ((t > 0) ? sdata[t - 1] : 0);
    if (idx < n_nodes) offs[idx] = excl;
}

// ---------------------------------------------------------------------------
// Atomic-free scatter: pos = offs[dst] + rank[e]  (unique by construction).
// Writes packed (edge_id, src) so gather never touches ei.
// ---------------------------------------------------------------------------
__global__ __launch_bounds__(256) void scatter_kernel(
    const int* __restrict__ ei,
    const int* __restrict__ rank,
    const int* __restrict__ offs,
    int2* __restrict__ edges_sorted,
    int n_edges)
{
    int e = blockIdx.x * blockDim.x + threadIdx.x;
    if (e < n_edges) {
        int s = ei[e];
        int d = ei[n_edges + e];
        int pos = offs[d] + rank[e];
        edges_sorted[pos] = make_int2(e, s);
    }
}

// ---------------------------------------------------------------------------
// Gather-aggregate. Layer-2 stays hoisted (hsum = Σ relu(h); W2 applied
// per-node in node_upd). OCCUPANCY FIX vs prev round: the 64 h-components
// are split across the 4 WAVES of the block (wave w owns comps [16w,16w+16)),
// so hacc shrinks 64 -> 16 VGPRs. The component-quarter is wave-uniform
// (readfirstlane) so W1E weight addresses remain SGPR-based (s_load), not
// per-lane VMEM. Each wave: 4 nodes x 16 edge-slots, same as before.
// Sibling waves re-read ef/edges_sorted for the same edges -> same-CU L1 hits.
// ---------------------------------------------------------------------------
__global__ __launch_bounds__(256, 6) void gather_kernel(
    const float* __restrict__ ef,
    const v2h*  __restrict__ W1Ep,
    const float* __restrict__ P1,
    const unsigned short* __restrict__ P2b,
    const int*  __restrict__ deg,
    const int*  __restrict__ offs,
    const int2* __restrict__ edges_sorted,
    float* __restrict__ hagg,
    int n_nodes)
{
    const int lane = threadIdx.x & 63;
    const int cg   = __builtin_amdgcn_readfirstlane((int)(threadIdx.x >> 6)); // comp quarter
    const int g    = lane >> 4;        // node sub-index in block
    const int t    = lane & 15;        // edge slot
    const int n    = blockIdx.x * 4 + g;
    if (n >= n_nodes) return;

    const int start = offs[n];
    const int end   = start + deg[n];

    // per-node P1 slice for this wave's 16 components (loop-invariant, hoisted)
    float p1q[16];
    {
        const float4* pp = (const float4*)(P1 + (size_t)n * D_H + cg * 16);
#pragma unroll
        for (int q = 0; q < 4; ++q) {
            float4 v = pp[q];
            p1q[4 * q + 0] = v.x; p1q[4 * q + 1] = v.y;
            p1q[4 * q + 2] = v.z; p1q[4 * q + 3] = v.w;
        }
    }

    const v2h* wbase = W1Ep + 16 * cg;   // wave-uniform -> scalar base

    float hacc[16];
#pragma unroll
    for (int c = 0; c < 16; ++c) hacc[c] = 0.0f;

    for (int i = start + t; i < end; i += 16) {
        int2 es = edges_sorted[i];
        const float4* efp = (const float4*)(ef + (size_t)es.x * D_EF);
        float4 f0 = efp[0], f1 = efp[1], f2 = efp[2], f3 = efp[3];
        const uint4* p2u = (const uint4*)(P2b + (size_t)es.y * D_H + cg * 16);
        uint4 b0 = p2u[0], b1 = p2u[1];

        v2h efh[D_EF / 2];
        efh[0] = __builtin_amdgcn_cvt_pkrtz(f0.x, f0.y);
        efh[1] = __builtin_amdgcn_cvt_pkrtz(f0.z, f0.w);
        efh[2] = __builtin_amdgcn_cvt_pkrtz(f1.x, f1.y);
        efh[3] = __builtin_amdgcn_cvt_pkrtz(f1.z, f1.w);
        efh[4] = __builtin_amdgcn_cvt_pkrtz(f2.x, f2.y);
        efh[5] = __builtin_amdgcn_cvt_pkrtz(f2.z, f2.w);
        efh[6] = __builtin_amdgcn_cvt_pkrtz(f3.x, f3.y);
        efh[7] = __builtin_amdgcn_cvt_pkrtz(f3.z, f3.w);

#pragma unroll
        for (int jj = 0; jj < 2; ++jj) {
            uint4 b = jj ? b1 : b0;
            float h[8];
            h[0] = p1q[8 * jj + 0] + bf_lo(b.x);
            h[1] = p1q[8 * jj + 1] + bf_hi(b.x);
            h[2] = p1q[8 * jj + 2] + bf_lo(b.y);
            h[3] = p1q[8 * jj + 3] + bf_hi(b.y);
            h[4] = p1q[8 * jj + 4] + bf_lo(b.z);
            h[5] = p1q[8 * jj + 5] + bf_hi(b.z);
            h[6] = p1q[8 * jj + 6] + bf_lo(b.w);
            h[7] = p1q[8 * jj + 7] + bf_hi(b.w);

            // layer-1: h[c] += ef · W1E[:, 16cg + 8jj + c]
#pragma unroll
            for (int kp = 0; kp < D_EF / 2; ++kp) {
                const v2h* wr = wbase + kp * D_H + 8 * jj;
#pragma unroll
                for (int c8 = 0; c8 < 8; ++c8)
                    h[c8] = __builtin_amdgcn_fdot2(efh[kp], wr[c8], h[c8], false);
            }

#pragma unroll
            for (int c8 = 0; c8 < 8; ++c8) {
                float r = h[c8] > 0.0f ? h[c8] : 0.0f;
                hacc[8 * jj + c8] += r;
            }
        }
    }

    // ---- 4-stage butterfly compaction across the node's 16 lanes ----
    // stage k splits comp-bit by lane-bit; final: lane t owns comp t.
    float r1[8];
    {
        const bool up = (t & 8) != 0;
#pragma unroll
        for (int c = 0; c < 8; ++c) {
            float lo = hacc[c]     + __shfl_xor(hacc[c],     8, 16);
            float hi = hacc[c + 8] + __shfl_xor(hacc[c + 8], 8, 16);
            r1[c] = up ? hi : lo;
        }
    }
    float r2[4];
    {
        const bool up = (t & 4) != 0;
#pragma unroll
        for (int c = 0; c < 4; ++c) {
            float lo = r1[c]     + __shfl_xor(r1[c],     4, 16);
            float hi = r1[c + 4] + __shfl_xor(r1[c + 4], 4, 16);
            r2[c] = up ? hi : lo;
        }
    }
    float r3[2];
    {
        const bool up = (t & 2) != 0;
#pragma unroll
        for (int c = 0; c < 2; ++c) {
            float lo = r2[c]     + __shfl_xor(r2[c],     2, 16);
            float hi = r2[c + 2] + __shfl_xor(r2[c + 2], 2, 16);
            r3[c] = up ? hi : lo;
        }
    }
    float r4;
    {
        const bool up = (t & 1) != 0;
        float lo = r3[0] + __shfl_xor(r3[0], 1, 16);
        float hi = r3[1] + __shfl_xor(r3[1], 1, 16);
        r4 = up ? hi : lo;
    }

    // lane t holds comp t of this wave's quarter -> coalesced 64B per group
    hagg[(size_t)n * D_H + cg * 16 + t] = r4;
}

// ---------------------------------------------------------------------------
// Per-node update MLP. Absorbs the hoisted layer-2:
//   aggm = hsum @ W2m + deg*b2m          (2048 MACs/node, once per NODE)
//   out  = relu([x, aggm] @ W1u + b1u) @ W2u + b2u
// ---------------------------------------------------------------------------
__global__ __launch_bounds__(256) void node_upd_kernel(
    const float* __restrict__ x,
    const float* __restrict__ hagg,
    const int*   __restrict__ deg,
    const float* __restrict__ b2m,
    const float* __restrict__ W2m,
    const float* __restrict__ W1u,
    const float* __restrict__ b1u,
    const float* __restrict__ W2u,
    const float* __restrict__ b2u,
    float* __restrict__ out,
    int n_nodes)
{
    int i = blockIdx.x * blockDim.x + threadIdx.x;
    if (i >= n_nodes) return;

    float in[D_IN + D_MSG];
    const float4* xp = (const float4*)(x + (size_t)i * D_IN);
#pragma unroll
    for (int k4 = 0; k4 < D_IN / 4; ++k4) {
        float4 v = xp[k4];
        in[4 * k4 + 0] = v.x; in[4 * k4 + 1] = v.y;
        in[4 * k4 + 2] = v.z; in[4 * k4 + 3] = v.w;
    }

    float dc = (float)deg[i];
#pragma unroll
    for (int m = 0; m < D_MSG; ++m) in[D_IN + m] = dc * b2m[m];

    const float4* hp = (const float4*)(hagg + (size_t)i * D_H);
    for (int j4 = 0; j4 < D_H / 4; ++j4) {
        float4 v = hp[j4];
        const float* w0 = W2m + (size_t)(4 * j4 + 0) * D_MSG;
        const float* w1 = W2m + (size_t)(4 * j4 + 1) * D_MSG;
        const float* w2 = W2m + (size_t)(4 * j4 + 2) * D_MSG;
        const float* w3 = W2m + (size_t)(4 * j4 + 3) * D_MSG;
#pragma unroll
        for (int m = 0; m < D_MSG; ++m)
            in[D_IN + m] += v.x * w0[m] + v.y * w1[m] + v.z * w2[m] + v.w * w3[m];
    }

    float h[D_H];
#pragma unroll
    for (int j = 0; j < D_H; ++j) h[j] = b1u[j];
    for (int k = 0; k < D_IN + D_MSG; ++k) {
        float v = in[k];
        const float* wr = W1u + (size_t)k * D_H;
#pragma unroll
        for (int j = 0; j < D_H; ++j) h[j] += v * wr[j];
    }

    float o[D_UP];
#pragma unroll
    for (int m = 0; m < D_UP; ++m) o[m] = b2u[m];
    for (int j = 0; j < D_H; ++j) {
        float r = h[j] > 0.0f ? h[j] : 0.0f;
        const float* wr = W2u + (size_t)j * D_UP;
#pragma unroll
        for (int m = 0; m < D_UP; ++m) o[m] += r * wr[m];
    }

    float4* op = (float4*)(out + (size_t)i * D_UP);
#pragma unroll
    for (int m4 = 0; m4 < D_UP / 4; ++m4)
        op[m4] = make_float4(o[4 * m4], o[4 * m4 + 1], o[4 * m4 + 2], o[4 * m4 + 3]);
}

extern "C" void kernel_launch(void* const* d_in, const int* in_sizes, int n_in,
                              void* d_out, int out_size, void* d_ws, size_t ws_size,
                              hipStream_t stream) {
    const float* x    = (const float*)d_in[0];
    // d_in[1] = degrees — unused by the reference computation
    const float* ef   = (const float*)d_in[2];
    const float* W1m  = (const float*)d_in[3];
    const float* b1m  = (const float*)d_in[4];
    const float* W2m  = (const float*)d_in[5];
    const float* b2m  = (const float*)d_in[6];
    const float* W1u  = (const float*)d_in[7];
    const float* b1u  = (const float*)d_in[8];
    const float* W2u  = (const float*)d_in[9];
    const float* b2u  = (const float*)d_in[10];
    const int*   ei   = (const int*)d_in[11];

    const int n_nodes = in_sizes[0] / D_IN;      // 50000
    const int n_edges = in_sizes[11] / 2;        // 1600000

    float* out = (float*)d_out;

    const int NBn = (n_nodes + 255) / 256;       // 196 node blocks (<=256 req'd for scan)
    const int NBe = (n_edges + 255) / 256;       // 6250 edge blocks

    // Workspace layout:
    //   P1           : n_nodes * D_H    f    (12.8 MB)
    //   P2b          : n_nodes * D_H    u16  (6.4 MB)
    //   edges_sorted : n_edges          int2 (12.8 MB)
    //   deg/offs     : n_nodes          i
    //   bsum/boffs   : NBn              i
    //   W1Ep         : 8*64   v2h (2 KB)
    //   tail (ALIASED by lifetime):
    //     rank : n_edges i     (6.4 MB,  live prep -> scatter)
    //     hagg : n_nodes*D_H f (12.8 MB, live gather -> node_upd)
    float*          P1  = (float*)d_ws;
    unsigned short* P2b = (unsigned short*)(P1 + (size_t)n_nodes * D_H);
    int2* edges_sorted  = (int2*)(P2b + (size_t)n_nodes * D_H);
    int* deg    = (int*)(edges_sorted + n_edges);
    int* offs   = deg    + n_nodes;
    int* bsum   = offs   + n_nodes;
    int* boffs  = bsum   + NBn;
    v2h* W1Ep   = (v2h*)(boffs + NBn);
    int*   rank = (int*)(W1Ep + 8 * D_H);
    float* hagg = (float*)rank;                  // aliases rank (disjoint lifetime)

    hipMemsetAsync(deg, 0, (size_t)n_nodes * sizeof(int), stream);

    prep_kernel<<<NBn + NBe + 1, 256, 0, stream>>>(
        x, W1m, b1m, ei, P1, P2b, deg, rank, W1Ep,
        n_nodes, n_edges, NBn, NBe);

    scan_partials_kernel<<<NBn, 256, 0, stream>>>(deg, bsum, n_nodes);
    scan_blockoffs_kernel<<<1, 256, 0, stream>>>(bsum, boffs, NBn);
    scan_final_kernel<<<NBn, 256, 0, stream>>>(deg, boffs, offs, n_nodes);

    scatter_kernel<<<NBe, 256, 0, stream>>>(ei, rank, offs, edges_sorted, n_edges);

    {
        // 4 nodes per block; all 4 waves of a block cover the same 4 nodes
        // (each wave a different component-quarter).
        int grid = (n_nodes + 3) / 4;
        gather_kernel<<<grid, 256, 0, stream>>>(ef, W1Ep, P1, P2b,
                                                deg, offs, edges_sorted, hagg,
                                                n_nodes);
    }
    node_upd_kernel<<<NBn, 256, 0, stream>>>(x, hagg, deg, b2m, W2m,
                                             W1u, b1u, W2u, b2u, out, n_nodes);
}